// Round 2
// baseline (172.446 us; speedup 1.0000x reference)
//
#include <hip/hip_runtime.h>
#include <hip/hip_bf16.h>

// RelativeAttention: out = softmax_j(mask((query@Wq)·(key@Wk)^T)) @ (key@Wv) @ Wu + bu
// B=4, T=1024, E=1024, H=8, D=128. All GEMMs via bf16 MFMA (f32 accum).

typedef __attribute__((ext_vector_type(8))) short bf16x8;   // 8 bf16 (4 VGPRs)
typedef __attribute__((ext_vector_type(4))) float f32x4;    // MFMA C/D frag

static constexpr int BB = 4;
static constexpr int TT = 1024;
static constexpr int EE = 1024;
static constexpr int HH = 8;
static constexpr int DD = 128;

// ---------- helpers ----------
static __device__ __forceinline__ unsigned short f2b(float x) {
  union { float f; unsigned int u; } c; c.f = x;
  unsigned int r = c.u + 0x7fffu + ((c.u >> 16) & 1u);   // RTN-even
  return (unsigned short)(r >> 16);
}

static __device__ __forceinline__ void gload_lds16(const void* g, void* l) {
  __builtin_amdgcn_global_load_lds(
      (const __attribute__((address_space(1))) unsigned int*)g,
      (__attribute__((address_space(3))) unsigned int*)l, 16, 0, 0);
}

// ---------- f32 -> bf16 convert for query & key ----------
__global__ __launch_bounds__(256) void cvt_kernel(
    const float* __restrict__ qf, const float* __restrict__ kf,
    unsigned short* __restrict__ qb, unsigned short* __restrict__ kb) {
  int i = blockIdx.x * 256 + threadIdx.x;   // each thread: 4 elements of each
  float4 a = ((const float4*)qf)[i];
  ushort4 oa; oa.x = f2b(a.x); oa.y = f2b(a.y); oa.z = f2b(a.z); oa.w = f2b(a.w);
  ((ushort4*)qb)[i] = oa;
  float4 b = ((const float4*)kf)[i];
  ushort4 ob; ob.x = f2b(b.x); ob.y = f2b(b.y); ob.z = f2b(b.z); ob.w = f2b(b.w);
  ((ushort4*)kb)[i] = ob;
}

// ---------- weight transpose-convert: W (K x N) f32 -> Wt (N x K) bf16 ----------
struct WT4 { const float* src[4]; unsigned short* dst[4]; };

__global__ __launch_bounds__(256) void wtrans_kernel(WT4 wt) {
  const float* src = wt.src[blockIdx.z];
  unsigned short* dst = wt.dst[blockIdx.z];
  __shared__ float tile[32][33];
  int n0 = blockIdx.x * 32, k0 = blockIdx.y * 32;
  int tx = threadIdx.x, ty = threadIdx.y;   // (32, 8)
#pragma unroll
  for (int i = 0; i < 4; ++i)
    tile[ty + i * 8][tx] = src[(size_t)(k0 + ty + i * 8) * EE + n0 + tx];
  __syncthreads();
#pragma unroll
  for (int i = 0; i < 4; ++i)
    dst[(size_t)(n0 + ty + i * 8) * EE + k0 + tx] = f2b(tile[tx][ty + i * 8]);
}

// ---------- V transpose: vp [b,kt, h*128+d] -> vt [b,h,d, kt] (bf16) ----------
__global__ __launch_bounds__(256) void vtrans_kernel(
    const unsigned short* __restrict__ vp, unsigned short* __restrict__ vt) {
  int bh = blockIdx.z; int b = bh >> 3, h = bh & 7;
  int d0 = blockIdx.x * 32, kt0 = blockIdx.y * 32;
  __shared__ unsigned short tile[32][33];
  int tx = threadIdx.x, ty = threadIdx.y;
#pragma unroll
  for (int i = 0; i < 4; ++i)
    tile[ty + i * 8][tx] =
        vp[(size_t)(b * TT + kt0 + ty + i * 8) * EE + h * DD + d0 + tx];
  __syncthreads();
#pragma unroll
  for (int i = 0; i < 4; ++i)
    vt[(size_t)((b * HH + h) * DD + d0 + ty + i * 8) * TT + kt0 + tx] =
        tile[tx][ty + i * 8];
}

// ---------- GEMM core: C[M,N] = A[M,K] @ Bt[N,K]^T  (m97 structure) ----------
// 128x128 tile, BK=32, 4 waves (2x2), 4x4 16x16 fragments per wave.
static __device__ __forceinline__ void gemm_core(
    const unsigned short* __restrict__ A, const unsigned short* __restrict__ Bt,
    unsigned short* __restrict__ Cb, float* __restrict__ Cf,
    const float* __restrict__ bias) {
  constexpr int K = EE, N = EE;
  __shared__ __align__(16) unsigned short As[128 * 32];
  __shared__ __align__(16) unsigned short Bs[128 * 32];
  const int tid = threadIdx.x, lane = tid & 63, w = tid >> 6;
  const int wm = w >> 1, wn = w & 1;
  const int bm = blockIdx.x, bn = blockIdx.y;
  const int g4 = lane >> 4, l15 = lane & 15;
  const int srow = lane >> 2;            // 0..15 (row within 16-row chunk)
  const int scol = (lane & 3) * 8;       // bf16 elems within 64B row

  f32x4 acc[4][4] = {};

  for (int kt = 0; kt < K / 32; ++kt) {
    const int k0 = kt * 32;
#pragma unroll
    for (int it = 0; it < 2; ++it) {
      int r = it * 64 + w * 16;
      gload_lds16(A + (size_t)(bm * 128 + r + srow) * K + k0 + scol, As + r * 32);
      gload_lds16(Bt + (size_t)(bn * 128 + r + srow) * K + k0 + scol, Bs + r * 32);
    }
    __syncthreads();
    bf16x8 af[4], bf[4];
#pragma unroll
    for (int i = 0; i < 4; ++i) {
      af[i] = *(const bf16x8*)(As + (wm * 64 + i * 16 + l15) * 32 + g4 * 8);
      bf[i] = *(const bf16x8*)(Bs + (wn * 64 + i * 16 + l15) * 32 + g4 * 8);
    }
#pragma unroll
    for (int i = 0; i < 4; ++i)
#pragma unroll
      for (int j = 0; j < 4; ++j)
        acc[i][j] = __builtin_amdgcn_mfma_f32_16x16x32_bf16(af[i], bf[j],
                                                            acc[i][j], 0, 0, 0);
    __syncthreads();
  }

  // epilogue: C/D layout col=lane&15, row=(lane>>4)*4+reg
  const int rr = g4 * 4;
#pragma unroll
  for (int i = 0; i < 4; ++i) {
#pragma unroll
    for (int j = 0; j < 4; ++j) {
      int row = bm * 128 + wm * 64 + i * 16 + rr;
      int col = bn * 128 + wn * 64 + j * 16 + l15;
#pragma unroll
      for (int r = 0; r < 4; ++r) {
        float v = acc[i][j][r];
        if (Cf != nullptr)
          Cf[(size_t)(row + r) * N + col] = v + bias[col];
        else
          Cb[(size_t)(row + r) * N + col] = f2b(v);
      }
    }
  }
}

struct Gemm3 { const unsigned short* A[3]; const unsigned short* Bt[3];
               unsigned short* C[3]; };

__global__ __launch_bounds__(256) void proj_gemm_kernel(Gemm3 g) {
  int z = blockIdx.z;
  gemm_core(g.A[z], g.Bt[z], g.C[z], nullptr, nullptr);
}

__global__ __launch_bounds__(256) void out_gemm_kernel(
    const unsigned short* __restrict__ A, const unsigned short* __restrict__ Bt,
    float* __restrict__ Cf, const float* __restrict__ bias) {
  gemm_core(A, Bt, nullptr, Cf, bias);
}

// ---------- fused attention: per (q-tile of 64, head, batch) ----------
// 4 waves; wave owns 16 q-rows. KVBLK=64. Online softmax (defer-max THR=8).
// Double-buffered K/V LDS (single barrier/tile); async reg-staged prefetch.
__global__ __launch_bounds__(256) void attn_kernel(
    const unsigned short* __restrict__ q, const unsigned short* __restrict__ k,
    const unsigned short* __restrict__ vt, const int* __restrict__ mask,
    unsigned short* __restrict__ av) {
  extern __shared__ __align__(16) char smem[];
  unsigned short* Ks = (unsigned short*)smem;              // 2 x [64][128] swz
  unsigned short* Vs = (unsigned short*)(smem + 32768);    // 2 x [128][64] swz
  unsigned short* Ps = (unsigned short*)(smem + 65536);    // [4][16][72]

  const int tid = threadIdx.x, lane = tid & 63, w = tid >> 6;
  const int qt = blockIdx.x, h = blockIdx.y, b = blockIdx.z;
  const int i0 = qt * 64 + w * 16;
  const int g4 = lane >> 4, l15 = lane & 15;

  // hoist Q fragments (A-operand layout: row=lane&15, k=(lane>>4)*8+j)
  bf16x8 aq[4];
  {
    const unsigned short* qb =
        q + (size_t)(b * TT + i0 + l15) * EE + h * DD + g4 * 8;
#pragma unroll
    for (int kc = 0; kc < 4; ++kc) aq[kc] = *(const bf16x8*)(qb + kc * 32);
  }

  const unsigned short* kb0 = k + (size_t)(b * TT) * EE + h * DD;
  const unsigned short* vb0 = vt + (size_t)((b * HH + h) * DD) * TT;

  float4 kreg[4], vreg[4];
  auto stage_load = [&](int t) {
#pragma unroll
    for (int p = 0; p < 4; ++p) {
      int idx = p * 256 + tid;
      kreg[p] = *(const float4*)(kb0 +
          (size_t)(t * 64 + (idx >> 4)) * EE + (idx & 15) * 8);
      vreg[p] = *(const float4*)(vb0 +
          (size_t)(idx >> 3) * TT + t * 64 + (idx & 7) * 8);
    }
  };
  auto stage_write = [&](int bsel) {
    unsigned short* Kd = Ks + bsel * 64 * 128;
    unsigned short* Vd = Vs + bsel * 128 * 64;
#pragma unroll
    for (int p = 0; p < 4; ++p) {
      int idx = p * 256 + tid;
      int krow = idx >> 4, kc16 = idx & 15;
      *(float4*)((char*)Kd + ((krow * 256 + kc16 * 16) ^ ((krow & 7) << 4))) =
          kreg[p];
      int vrow = idx >> 3, vc16 = idx & 7;
      *(float4*)((char*)Vd + ((vrow * 128 + vc16 * 16) ^ ((vrow & 7) << 4))) =
          vreg[p];
    }
  };

  f32x4 oacc[8] = {};
  float mrun[4], lrun[4];
#pragma unroll
  for (int r = 0; r < 4; ++r) { mrun[r] = -__builtin_inff(); lrun[r] = 0.f; }

  stage_load(0);
  stage_write(0);
  __syncthreads();
  int buf = 0;

  for (int t = 0; t < 16; ++t) {
    // ---- prefetch next K/V tile into regs (latency hides under compute) ----
    if (t < 15) stage_load(t + 1);

    // ---- prefetch mask for this tile into regs ----
    int mreg[4][4];
    {
      const int* mrow =
          mask + (size_t)(b * TT + i0 + g4 * 4) * TT + t * 64 + l15;
#pragma unroll
      for (int r = 0; r < 4; ++r)
#pragma unroll
        for (int nt = 0; nt < 4; ++nt)
          mreg[r][nt] = mrow[(size_t)r * TT + nt * 16];
    }

    const unsigned short* Kb = Ks + buf * 64 * 128;
    const unsigned short* Vb = Vs + buf * 128 * 64;

    // ---- S = Q K^T (16 x 64 per wave) ----
    f32x4 sacc[4];
    __builtin_amdgcn_s_setprio(1);
#pragma unroll
    for (int nt = 0; nt < 4; ++nt) {
      f32x4 s = {};
#pragma unroll
      for (int kc = 0; kc < 4; ++kc) {
        int krow = nt * 16 + l15;
        int addr = (krow * 256 + (kc * 32 + g4 * 8) * 2) ^ ((krow & 7) << 4);
        bf16x8 bk = *(const bf16x8*)((const char*)Kb + addr);
        s = __builtin_amdgcn_mfma_f32_16x16x32_bf16(aq[kc], bk, s, 0, 0, 0);
      }
      sacc[nt] = s;
    }
    __builtin_amdgcn_s_setprio(0);

    // ---- mask (mask==0 -> -1e9, matching reference exactly) ----
    // S layout: q-row i = g4*4 + r, kt col j = nt*16 + l15
#pragma unroll
    for (int r = 0; r < 4; ++r)
#pragma unroll
      for (int nt = 0; nt < 4; ++nt)
        if (mreg[r][nt] == 0) sacc[nt][r] = -1e9f;

    // ---- online softmax with defer-max (THR=8) ----
    float tmx[4];
#pragma unroll
    for (int r = 0; r < 4; ++r) {
      float mx = fmaxf(fmaxf(sacc[0][r], sacc[1][r]),
                       fmaxf(sacc[2][r], sacc[3][r]));
#pragma unroll
      for (int d = 1; d < 16; d <<= 1) mx = fmaxf(mx, __shfl_xor(mx, d, 64));
      tmx[r] = mx;
    }
    bool need = (tmx[0] > mrun[0] + 8.f) || (tmx[1] > mrun[1] + 8.f) ||
                (tmx[2] > mrun[2] + 8.f) || (tmx[3] > mrun[3] + 8.f);
    if (__any(need)) {
#pragma unroll
      for (int r = 0; r < 4; ++r) {
        float mnew = fmaxf(mrun[r], tmx[r]);
        float sc = __expf(mrun[r] - mnew);   // exp(-inf)=0 on first tile
        lrun[r] *= sc;
        mrun[r] = mnew;
#pragma unroll
        for (int dt = 0; dt < 8; ++dt) oacc[dt][r] *= sc;
      }
    }
#pragma unroll
    for (int r = 0; r < 4; ++r) {
      float s0 = 0.f;
#pragma unroll
      for (int nt = 0; nt < 4; ++nt) {
        float pv = __expf(sacc[nt][r] - mrun[r]);   // bounded by e^8
        Ps[(w * 16 + g4 * 4 + r) * 72 + nt * 16 + l15] = f2b(pv);
        s0 += pv;
      }
#pragma unroll
      for (int d = 1; d < 16; d <<= 1) s0 += __shfl_xor(s0, d, 64);
      lrun[r] += s0;
    }

    // ---- PV: O += P (16x64) @ V (64x128) ---- (Ps is per-wave: no barrier)
    __builtin_amdgcn_s_setprio(1);
#pragma unroll
    for (int kc2 = 0; kc2 < 2; ++kc2) {
      bf16x8 pa = *(const bf16x8*)(Ps + (w * 16 + l15) * 72 + kc2 * 32 + g4 * 8);
#pragma unroll
      for (int dt = 0; dt < 8; ++dt) {
        int vrow = dt * 16 + l15;
        int addr = (vrow * 128 + (kc2 * 32 + g4 * 8) * 2) ^ ((vrow & 7) << 4);
        bf16x8 bv = *(const bf16x8*)((const char*)Vb + addr);
        oacc[dt] = __builtin_amdgcn_mfma_f32_16x16x32_bf16(pa, bv, oacc[dt],
                                                           0, 0, 0);
      }
    }
    __builtin_amdgcn_s_setprio(0);

    // ---- write prefetched tile into the other buffer, then one barrier ----
    if (t < 15) stage_write(buf ^ 1);
    __syncthreads();
    buf ^= 1;
  }

  // ---- epilogue: att_vec = O / l ----
  float inv[4];
#pragma unroll
  for (int r = 0; r < 4; ++r) inv[r] = 1.f / lrun[r];
  unsigned short* ob =
      av + (size_t)(b * TT + i0 + g4 * 4) * EE + h * DD + l15;
#pragma unroll
  for (int dt = 0; dt < 8; ++dt)
#pragma unroll
    for (int r = 0; r < 4; ++r)
      ob[(size_t)r * EE + dt * 16] = f2b(oacc[dt][r] * inv[r]);
}

// ---------- launch ----------
extern "C" void kernel_launch(void* const* d_in, const int* in_sizes, int n_in,
                              void* d_out, int out_size, void* d_ws,
                              size_t ws_size, hipStream_t stream) {
  const float* query = (const float*)d_in[0];
  const float* key   = (const float*)d_in[1];
  const int*   mask  = (const int*)d_in[2];
  const float* Wq    = (const float*)d_in[3];
  const float* Wk    = (const float*)d_in[4];
  const float* Wv    = (const float*)d_in[5];
  const float* Wu    = (const float*)d_in[6];
  const float* bu    = (const float*)d_in[7];
  float* out = (float*)d_out;

  char* ws = (char*)d_ws;
  const size_t MB = 1024 * 1024;
  unsigned short* qbf = (unsigned short*)(ws);             // 8MB bf16 query
  unsigned short* kbf = (unsigned short*)(ws + 8 * MB);    // 8MB bf16 key
  unsigned short* Wqt = (unsigned short*)(ws + 16 * MB);   // 2MB each, N x K
  unsigned short* Wkt = (unsigned short*)(ws + 18 * MB);
  unsigned short* Wvt = (unsigned short*)(ws + 20 * MB);
  unsigned short* Wut = (unsigned short*)(ws + 22 * MB);
  unsigned short* qp  = (unsigned short*)(ws + 24 * MB);   // q proj
  unsigned short* kp  = (unsigned short*)(ws + 32 * MB);   // k proj
  unsigned short* vp  = (unsigned short*)(ws + 40 * MB);   // v proj
  unsigned short* vtb = (unsigned short*)(ws + 48 * MB);   // v transposed
  unsigned short* av  = (unsigned short*)(ws + 56 * MB);   // attention out

  cvt_kernel<<<4096, 256, 0, stream>>>(query, key, qbf, kbf);

  WT4 wt; wt.src[0] = Wq; wt.src[1] = Wk; wt.src[2] = Wv; wt.src[3] = Wu;
  wt.dst[0] = Wqt; wt.dst[1] = Wkt; wt.dst[2] = Wvt; wt.dst[3] = Wut;
  wtrans_kernel<<<dim3(32, 32, 4), dim3(32, 8), 0, stream>>>(wt);

  Gemm3 g3;
  g3.A[0] = qbf; g3.A[1] = kbf; g3.A[2] = kbf;
  g3.Bt[0] = Wqt; g3.Bt[1] = Wkt; g3.Bt[2] = Wvt;
  g3.C[0] = qp; g3.C[1] = kp; g3.C[2] = vp;
  proj_gemm_kernel<<<dim3(32, 8, 3), 256, 0, stream>>>(g3);

  vtrans_kernel<<<dim3(4, 32, 32), dim3(32, 8), 0, stream>>>(vp, vtb);

  attn_kernel<<<dim3(16, 8, 4), 256, 74752, stream>>>(qp, kp, vtb, mask, av);

  out_gemm_kernel<<<dim3(32, 8), 256, 0, stream>>>(av, Wut, out, bu);
}

// Round 3
// 133.380 us; speedup vs baseline: 1.2929x; 1.2929x over previous
//
#include <hip/hip_runtime.h>
#include <hip/hip_bf16.h>

// RelativeAttention: out = softmax_j(mask((query@Wq)·(key@Wk)^T)) @ (key@Wv) @ Wu + bu
// B=4, T=1024, E=1024, H=8, D=128. All GEMMs via bf16 MFMA (f32 accum).

typedef __attribute__((ext_vector_type(8))) short bf16x8;   // 8 bf16 (4 VGPRs)
typedef __attribute__((ext_vector_type(4))) float f32x4;    // MFMA C/D frag

static constexpr int BB = 4;
static constexpr int TT = 1024;
static constexpr int EE = 1024;
static constexpr int HH = 8;
static constexpr int DD = 128;

// ---------- helpers ----------
static __device__ __forceinline__ unsigned short f2b(float x) {
  union { float f; unsigned int u; } c; c.f = x;
  unsigned int r = c.u + 0x7fffu + ((c.u >> 16) & 1u);   // RTN-even
  return (unsigned short)(r >> 16);
}

static __device__ __forceinline__ void gload_lds16(const void* g, void* l) {
  __builtin_amdgcn_global_load_lds(
      (const __attribute__((address_space(1))) unsigned int*)g,
      (__attribute__((address_space(3))) unsigned int*)l, 16, 0, 0);
}

// ---------- f32 -> bf16 convert for query & key ----------
__global__ __launch_bounds__(256) void cvt_kernel(
    const float* __restrict__ qf, const float* __restrict__ kf,
    unsigned short* __restrict__ qb, unsigned short* __restrict__ kb) {
  int i = blockIdx.x * 256 + threadIdx.x;   // each thread: 4 elements of each
  float4 a = ((const float4*)qf)[i];
  ushort4 oa; oa.x = f2b(a.x); oa.y = f2b(a.y); oa.z = f2b(a.z); oa.w = f2b(a.w);
  ((ushort4*)qb)[i] = oa;
  float4 b = ((const float4*)kf)[i];
  ushort4 ob; ob.x = f2b(b.x); ob.y = f2b(b.y); ob.z = f2b(b.z); ob.w = f2b(b.w);
  ((ushort4*)kb)[i] = ob;
}

// ---------- weight transpose-convert: W (K x N) f32 -> Wt (N x K) bf16 ----------
struct WT4 { const float* src[4]; unsigned short* dst[4]; };

__global__ __launch_bounds__(256) void wtrans_kernel(WT4 wt) {
  const float* src = wt.src[blockIdx.z];
  unsigned short* dst = wt.dst[blockIdx.z];
  __shared__ float tile[32][33];
  int n0 = blockIdx.x * 32, k0 = blockIdx.y * 32;
  int tx = threadIdx.x, ty = threadIdx.y;   // (32, 8)
#pragma unroll
  for (int i = 0; i < 4; ++i)
    tile[ty + i * 8][tx] = src[(size_t)(k0 + ty + i * 8) * EE + n0 + tx];
  __syncthreads();
#pragma unroll
  for (int i = 0; i < 4; ++i)
    dst[(size_t)(n0 + ty + i * 8) * EE + k0 + tx] = f2b(tile[tx][ty + i * 8]);
}

// ---------- V transpose: vp [b,kt, h*128+d] -> vt [b,h,d, kt] (bf16) ----------
__global__ __launch_bounds__(256) void vtrans_kernel(
    const unsigned short* __restrict__ vp, unsigned short* __restrict__ vt) {
  int bh = blockIdx.z; int b = bh >> 3, h = bh & 7;
  int d0 = blockIdx.x * 32, kt0 = blockIdx.y * 32;
  __shared__ unsigned short tile[32][33];
  int tx = threadIdx.x, ty = threadIdx.y;
#pragma unroll
  for (int i = 0; i < 4; ++i)
    tile[ty + i * 8][tx] =
        vp[(size_t)(b * TT + kt0 + ty + i * 8) * EE + h * DD + d0 + tx];
  __syncthreads();
#pragma unroll
  for (int i = 0; i < 4; ++i)
    vt[(size_t)((b * HH + h) * DD + d0 + ty + i * 8) * TT + kt0 + tx] =
        tile[tx][ty + i * 8];
}

// ---------- GEMM core: C[M,N] = A[M,K] @ Bt[N,K]^T  (m97 structure) ----------
// 128x128 tile, BK=32, 4 waves (2x2), 4x4 16x16 fragments per wave.
static __device__ __forceinline__ void gemm_core(
    const unsigned short* __restrict__ A, const unsigned short* __restrict__ Bt,
    unsigned short* __restrict__ Cb, float* __restrict__ Cf,
    const float* __restrict__ bias) {
  constexpr int K = EE, N = EE;
  __shared__ __align__(16) unsigned short As[128 * 32];
  __shared__ __align__(16) unsigned short Bs[128 * 32];
  const int tid = threadIdx.x, lane = tid & 63, w = tid >> 6;
  const int wm = w >> 1, wn = w & 1;
  const int bm = blockIdx.x, bn = blockIdx.y;
  const int g4 = lane >> 4, l15 = lane & 15;
  const int srow = lane >> 2;            // 0..15 (row within 16-row chunk)
  const int scol = (lane & 3) * 8;       // bf16 elems within 64B row

  f32x4 acc[4][4] = {};

  for (int kt = 0; kt < K / 32; ++kt) {
    const int k0 = kt * 32;
#pragma unroll
    for (int it = 0; it < 2; ++it) {
      int r = it * 64 + w * 16;
      gload_lds16(A + (size_t)(bm * 128 + r + srow) * K + k0 + scol, As + r * 32);
      gload_lds16(Bt + (size_t)(bn * 128 + r + srow) * K + k0 + scol, Bs + r * 32);
    }
    __syncthreads();
    bf16x8 af[4], bf[4];
#pragma unroll
    for (int i = 0; i < 4; ++i) {
      af[i] = *(const bf16x8*)(As + (wm * 64 + i * 16 + l15) * 32 + g4 * 8);
      bf[i] = *(const bf16x8*)(Bs + (wn * 64 + i * 16 + l15) * 32 + g4 * 8);
    }
#pragma unroll
    for (int i = 0; i < 4; ++i)
#pragma unroll
      for (int j = 0; j < 4; ++j)
        acc[i][j] = __builtin_amdgcn_mfma_f32_16x16x32_bf16(af[i], bf[j],
                                                            acc[i][j], 0, 0, 0);
    __syncthreads();
  }

  // epilogue: C/D layout col=lane&15, row=(lane>>4)*4+reg
  const int rr = g4 * 4;
#pragma unroll
  for (int i = 0; i < 4; ++i) {
#pragma unroll
    for (int j = 0; j < 4; ++j) {
      int row = bm * 128 + wm * 64 + i * 16 + rr;
      int col = bn * 128 + wn * 64 + j * 16 + l15;
#pragma unroll
      for (int r = 0; r < 4; ++r) {
        float v = acc[i][j][r];
        if (Cf != nullptr)
          Cf[(size_t)(row + r) * N + col] = v + bias[col];
        else
          Cb[(size_t)(row + r) * N + col] = f2b(v);
      }
    }
  }
}

struct Gemm3 { const unsigned short* A[3]; const unsigned short* Bt[3];
               unsigned short* C[3]; };

__global__ __launch_bounds__(256) void proj_gemm_kernel(Gemm3 g) {
  int z = blockIdx.z;
  gemm_core(g.A[z], g.Bt[z], g.C[z], nullptr, nullptr);
}

__global__ __launch_bounds__(256) void out_gemm_kernel(
    const unsigned short* __restrict__ A, const unsigned short* __restrict__ Bt,
    float* __restrict__ Cf, const float* __restrict__ bias) {
  gemm_core(A, Bt, nullptr, Cf, bias);
}

// ---------- fused attention: per (q-tile of 64, head, batch) ----------
// 4 waves; wave owns 16 q-rows. KVBLK=64. Online softmax (defer-max THR=8).
// Double-buffered K/V in LDS via async global_load_lds with pre-swizzled
// global source (linear LDS dest per guide m104/m173); 1 barrier/tile.
__global__ __launch_bounds__(256) void attn_kernel(
    const unsigned short* __restrict__ q, const unsigned short* __restrict__ k,
    const unsigned short* __restrict__ vt, const int* __restrict__ mask,
    unsigned short* __restrict__ av) {
  extern __shared__ __align__(16) char smem[];
  unsigned short* Ks = (unsigned short*)smem;              // 2 x [64][128] swz
  unsigned short* Vs = (unsigned short*)(smem + 32768);    // 2 x [128][64] swz
  unsigned short* Ps = (unsigned short*)(smem + 65536);    // [4][16][72]

  const int tid = threadIdx.x, lane = tid & 63, w = tid >> 6;
  const int qt = blockIdx.x, h = blockIdx.y, b = blockIdx.z;
  const int i0 = qt * 64 + w * 16;
  const int g4 = lane >> 4, l15 = lane & 15;

  // hoist Q fragments (A-operand layout: row=lane&15, k=(lane>>4)*8+j)
  bf16x8 aq[4];
  {
    const unsigned short* qb =
        q + (size_t)(b * TT + i0 + l15) * EE + h * DD + g4 * 8;
#pragma unroll
    for (int kc = 0; kc < 4; ++kc) aq[kc] = *(const bf16x8*)(qb + kc * 32);
  }

  const unsigned short* kb0 = k + (size_t)(b * TT) * EE + h * DD;
  const unsigned short* vb0 = vt + (size_t)((b * HH + h) * DD) * TT;

  // Async stage of tile t into buffer bsel. LDS dest is linear
  // (wave-uniform base + lane*16); the global SOURCE chunk index is
  // pre-swizzled with the inverse of the read swizzle (c ^= row&7) so
  // reads can use addr ^ ((row&7)<<4). XOR permutes 16B chunks within a
  // row -> source stays coalesced within one row segment.
  auto stage = [&](int t, int bsel) {
    unsigned short* Kd = Ks + bsel * (64 * 128);
    unsigned short* Vd = Vs + bsel * (128 * 64);
#pragma unroll
    for (int p = 0; p < 4; ++p) {
      int base = p * 256 + w * 64;           // wave-uniform 16B-chunk base
      int idx = base + lane;
      int kr = idx >> 4, kc = (idx & 15) ^ (kr & 7);
      gload_lds16(kb0 + (size_t)(t * 64 + kr) * EE + kc * 8, Kd + base * 8);
      int vr = idx >> 3, vc = (idx & 7) ^ (vr & 7);
      gload_lds16(vb0 + (size_t)vr * TT + t * 64 + vc * 8, Vd + base * 8);
    }
  };

  f32x4 oacc[8] = {};
  float mrun[4], lrun[4];
#pragma unroll
  for (int r = 0; r < 4; ++r) { mrun[r] = -__builtin_inff(); lrun[r] = 0.f; }

  stage(0, 0);
  __syncthreads();   // drains vmcnt -> tile 0 resident
  int buf = 0;

  for (int t = 0; t < 16; ++t) {
    // ---- async prefetch of next tile into the other buffer ----
    if (t < 15) stage(t + 1, buf ^ 1);

    // ---- prefetch mask for this tile into regs ----
    int mreg[4][4];
    {
      const int* mrow =
          mask + (size_t)(b * TT + i0 + g4 * 4) * TT + t * 64 + l15;
#pragma unroll
      for (int r = 0; r < 4; ++r)
#pragma unroll
        for (int nt = 0; nt < 4; ++nt)
          mreg[r][nt] = mrow[(size_t)r * TT + nt * 16];
    }

    const unsigned short* Kb = Ks + buf * 64 * 128;
    const unsigned short* Vb = Vs + buf * 128 * 64;

    // ---- S = Q K^T (16 x 64 per wave) ----
    f32x4 sacc[4];
    __builtin_amdgcn_s_setprio(1);
#pragma unroll
    for (int nt = 0; nt < 4; ++nt) {
      f32x4 s = {};
#pragma unroll
      for (int kc = 0; kc < 4; ++kc) {
        int krow = nt * 16 + l15;
        int addr = (krow * 256 + (kc * 32 + g4 * 8) * 2) ^ ((krow & 7) << 4);
        bf16x8 bk = *(const bf16x8*)((const char*)Kb + addr);
        s = __builtin_amdgcn_mfma_f32_16x16x32_bf16(aq[kc], bk, s, 0, 0, 0);
      }
      sacc[nt] = s;
    }
    __builtin_amdgcn_s_setprio(0);

    // ---- mask (mask==0 -> -1e9, matching reference exactly) ----
    // S layout: q-row i = g4*4 + r, kt col j = nt*16 + l15
#pragma unroll
    for (int r = 0; r < 4; ++r)
#pragma unroll
      for (int nt = 0; nt < 4; ++nt)
        if (mreg[r][nt] == 0) sacc[nt][r] = -1e9f;

    // ---- online softmax with defer-max (THR=8) ----
    float tmx[4];
#pragma unroll
    for (int r = 0; r < 4; ++r) {
      float mx = fmaxf(fmaxf(sacc[0][r], sacc[1][r]),
                       fmaxf(sacc[2][r], sacc[3][r]));
#pragma unroll
      for (int d = 1; d < 16; d <<= 1) mx = fmaxf(mx, __shfl_xor(mx, d, 64));
      tmx[r] = mx;
    }
    bool need = (tmx[0] > mrun[0] + 8.f) || (tmx[1] > mrun[1] + 8.f) ||
                (tmx[2] > mrun[2] + 8.f) || (tmx[3] > mrun[3] + 8.f);
    if (__any(need)) {
#pragma unroll
      for (int r = 0; r < 4; ++r) {
        float mnew = fmaxf(mrun[r], tmx[r]);
        float sc = __expf(mrun[r] - mnew);   // exp(-inf)=0 on first tile
        lrun[r] *= sc;
        mrun[r] = mnew;
#pragma unroll
        for (int dt = 0; dt < 8; ++dt) oacc[dt][r] *= sc;
      }
    }
#pragma unroll
    for (int r = 0; r < 4; ++r) {
      float s0 = 0.f;
#pragma unroll
      for (int nt = 0; nt < 4; ++nt) {
        float pv = __expf(sacc[nt][r] - mrun[r]);   // bounded by e^8
        Ps[(w * 16 + g4 * 4 + r) * 72 + nt * 16 + l15] = f2b(pv);
        s0 += pv;
      }
#pragma unroll
      for (int d = 1; d < 16; d <<= 1) s0 += __shfl_xor(s0, d, 64);
      lrun[r] += s0;
    }

    // ---- PV: O += P (16x64) @ V (64x128) ---- (Ps is per-wave: no barrier)
    __builtin_amdgcn_s_setprio(1);
#pragma unroll
    for (int kc2 = 0; kc2 < 2; ++kc2) {
      bf16x8 pa = *(const bf16x8*)(Ps + (w * 16 + l15) * 72 + kc2 * 32 + g4 * 8);
#pragma unroll
      for (int dt = 0; dt < 8; ++dt) {
        int vrow = dt * 16 + l15;
        int addr = (vrow * 128 + (kc2 * 32 + g4 * 8) * 2) ^ ((vrow & 7) << 4);
        bf16x8 bv = *(const bf16x8*)((const char*)Vb + addr);
        oacc[dt] = __builtin_amdgcn_mfma_f32_16x16x32_bf16(pa, bv, oacc[dt],
                                                           0, 0, 0);
      }
    }
    __builtin_amdgcn_s_setprio(0);

    // ---- one barrier: drains prefetch (vmcnt) + orders buffer reuse ----
    __syncthreads();
    buf ^= 1;
  }

  // ---- epilogue: att_vec = O / l ----
  float inv[4];
#pragma unroll
  for (int r = 0; r < 4; ++r) inv[r] = 1.f / lrun[r];
  unsigned short* ob =
      av + (size_t)(b * TT + i0 + g4 * 4) * EE + h * DD + l15;
#pragma unroll
  for (int dt = 0; dt < 8; ++dt)
#pragma unroll
    for (int r = 0; r < 4; ++r)
      ob[(size_t)r * EE + dt * 16] = f2b(oacc[dt][r] * inv[r]);
}

// ---------- launch ----------
extern "C" void kernel_launch(void* const* d_in, const int* in_sizes, int n_in,
                              void* d_out, int out_size, void* d_ws,
                              size_t ws_size, hipStream_t stream) {
  const float* query = (const float*)d_in[0];
  const float* key   = (const float*)d_in[1];
  const int*   mask  = (const int*)d_in[2];
  const float* Wq    = (const float*)d_in[3];
  const float* Wk    = (const float*)d_in[4];
  const float* Wv    = (const float*)d_in[5];
  const float* Wu    = (const float*)d_in[6];
  const float* bu    = (const float*)d_in[7];
  float* out = (float*)d_out;

  char* ws = (char*)d_ws;
  const size_t MB = 1024 * 1024;
  unsigned short* qbf = (unsigned short*)(ws);             // 8MB bf16 query
  unsigned short* kbf = (unsigned short*)(ws + 8 * MB);    // 8MB bf16 key
  unsigned short* Wqt = (unsigned short*)(ws + 16 * MB);   // 2MB each, N x K
  unsigned short* Wkt = (unsigned short*)(ws + 18 * MB);
  unsigned short* Wvt = (unsigned short*)(ws + 20 * MB);
  unsigned short* Wut = (unsigned short*)(ws + 22 * MB);
  unsigned short* qp  = (unsigned short*)(ws + 24 * MB);   // q proj
  unsigned short* kp  = (unsigned short*)(ws + 32 * MB);   // k proj
  unsigned short* vp  = (unsigned short*)(ws + 40 * MB);   // v proj
  unsigned short* vtb = (unsigned short*)(ws + 48 * MB);   // v transposed
  unsigned short* av  = (unsigned short*)(ws + 56 * MB);   // attention out

  cvt_kernel<<<4096, 256, 0, stream>>>(query, key, qbf, kbf);

  WT4 wt; wt.src[0] = Wq; wt.src[1] = Wk; wt.src[2] = Wv; wt.src[3] = Wu;
  wt.dst[0] = Wqt; wt.dst[1] = Wkt; wt.dst[2] = Wvt; wt.dst[3] = Wut;
  wtrans_kernel<<<dim3(32, 32, 4), dim3(32, 8), 0, stream>>>(wt);

  Gemm3 g3;
  g3.A[0] = qbf; g3.A[1] = kbf; g3.A[2] = kbf;
  g3.Bt[0] = Wqt; g3.Bt[1] = Wkt; g3.Bt[2] = Wvt;
  g3.C[0] = qp; g3.C[1] = kp; g3.C[2] = vp;
  proj_gemm_kernel<<<dim3(32, 8, 3), 256, 0, stream>>>(g3);

  vtrans_kernel<<<dim3(4, 32, 32), dim3(32, 8), 0, stream>>>(vp, vtb);

  attn_kernel<<<dim3(16, 8, 4), 256, 74752, stream>>>(qp, kp, vtb, mask, av);

  out_gemm_kernel<<<dim3(32, 8), 256, 0, stream>>>(av, Wut, out, bu);
}

// Round 5
// 126.655 us; speedup vs baseline: 1.3615x; 1.0531x over previous
//
#include <hip/hip_runtime.h>
#include <hip/hip_bf16.h>

// RelativeAttention: out = softmax_j(mask((query@Wq)·(key@Wk)^T)) @ (key@Wv) @ Wu + bu
// B=4, T=1024, E=1024, H=8, D=128. All GEMMs via bf16 MFMA (f32 accum).

typedef __attribute__((ext_vector_type(8))) short bf16x8;   // 8 bf16 (4 VGPRs)
typedef __attribute__((ext_vector_type(4))) float f32x4;    // MFMA C/D frag

static constexpr int BB = 4;
static constexpr int TT = 1024;
static constexpr int EE = 1024;
static constexpr int HH = 8;
static constexpr int DD = 128;

// ---------- helpers ----------
static __device__ __forceinline__ unsigned short f2b(float x) {
  union { float f; unsigned int u; } c; c.f = x;
  unsigned int r = c.u + 0x7fffu + ((c.u >> 16) & 1u);   // RTN-even
  return (unsigned short)(r >> 16);
}

static __device__ __forceinline__ unsigned int cvtpk(float lo, float hi) {
  unsigned int r;
  asm("v_cvt_pk_bf16_f32 %0, %1, %2" : "=v"(r) : "v"(lo), "v"(hi));
  return r;   // low16 = bf16(lo), high16 = bf16(hi)
}

static __device__ __forceinline__ void gload_lds16(const void* g, void* l) {
  __builtin_amdgcn_global_load_lds(
      (const __attribute__((address_space(1))) unsigned int*)g,
      (__attribute__((address_space(3))) unsigned int*)l, 16, 0, 0);
}

// ---------- f32 -> bf16 convert for query & key ----------
__global__ __launch_bounds__(256) void cvt_kernel(
    const float* __restrict__ qf, const float* __restrict__ kf,
    unsigned short* __restrict__ qb, unsigned short* __restrict__ kb) {
  int i = blockIdx.x * 256 + threadIdx.x;   // each thread: 4 elements of each
  float4 a = ((const float4*)qf)[i];
  ushort4 oa; oa.x = f2b(a.x); oa.y = f2b(a.y); oa.z = f2b(a.z); oa.w = f2b(a.w);
  ((ushort4*)qb)[i] = oa;
  float4 b = ((const float4*)kf)[i];
  ushort4 ob; ob.x = f2b(b.x); ob.y = f2b(b.y); ob.z = f2b(b.z); ob.w = f2b(b.w);
  ((ushort4*)kb)[i] = ob;
}

// ---------- weight transpose-convert: W (K x N) f32 -> Wt (N x K) bf16 ----------
struct WT4 { const float* src[4]; unsigned short* dst[4]; };

__global__ __launch_bounds__(256) void wtrans_kernel(WT4 wt) {
  const float* src = wt.src[blockIdx.z];
  unsigned short* dst = wt.dst[blockIdx.z];
  __shared__ float tile[32][33];
  int n0 = blockIdx.x * 32, k0 = blockIdx.y * 32;
  int tx = threadIdx.x, ty = threadIdx.y;   // (32, 8)
#pragma unroll
  for (int i = 0; i < 4; ++i)
    tile[ty + i * 8][tx] = src[(size_t)(k0 + ty + i * 8) * EE + n0 + tx];
  __syncthreads();
#pragma unroll
  for (int i = 0; i < 4; ++i)
    dst[(size_t)(n0 + ty + i * 8) * EE + k0 + tx] = f2b(tile[tx][ty + i * 8]);
}

// ---------- V transpose: vp [b,kt, h*128+d] -> vt [b,h,d, kt] (bf16) ----------
__global__ __launch_bounds__(256) void vtrans_kernel(
    const unsigned short* __restrict__ vp, unsigned short* __restrict__ vt) {
  int bh = blockIdx.z; int b = bh >> 3, h = bh & 7;
  int d0 = blockIdx.x * 32, kt0 = blockIdx.y * 32;
  __shared__ unsigned short tile[32][33];
  int tx = threadIdx.x, ty = threadIdx.y;
#pragma unroll
  for (int i = 0; i < 4; ++i)
    tile[ty + i * 8][tx] =
        vp[(size_t)(b * TT + kt0 + ty + i * 8) * EE + h * DD + d0 + tx];
  __syncthreads();
#pragma unroll
  for (int i = 0; i < 4; ++i)
    vt[(size_t)((b * HH + h) * DD + d0 + ty + i * 8) * TT + kt0 + tx] =
        tile[tx][ty + i * 8];
}

// ---------- GEMM core: C[M,N] = A[M,K] @ Bt[N,K]^T  (m97 structure) ----------
// 128x128 tile, BK=32, 4 waves (2x2), 4x4 16x16 fragments per wave.
static __device__ __forceinline__ void gemm_core(
    const unsigned short* __restrict__ A, const unsigned short* __restrict__ Bt,
    unsigned short* __restrict__ Cb, float* __restrict__ Cf,
    const float* __restrict__ bias) {
  constexpr int K = EE, N = EE;
  __shared__ __align__(16) unsigned short As[128 * 32];
  __shared__ __align__(16) unsigned short Bs[128 * 32];
  const int tid = threadIdx.x, lane = tid & 63, w = tid >> 6;
  const int wm = w >> 1, wn = w & 1;
  const int bm = blockIdx.x, bn = blockIdx.y;
  const int g4 = lane >> 4, l15 = lane & 15;
  const int srow = lane >> 2;            // 0..15 (row within 16-row chunk)
  const int scol = (lane & 3) * 8;       // bf16 elems within 64B row

  f32x4 acc[4][4] = {};

  for (int kt = 0; kt < K / 32; ++kt) {
    const int k0 = kt * 32;
#pragma unroll
    for (int it = 0; it < 2; ++it) {
      int r = it * 64 + w * 16;
      gload_lds16(A + (size_t)(bm * 128 + r + srow) * K + k0 + scol, As + r * 32);
      gload_lds16(Bt + (size_t)(bn * 128 + r + srow) * K + k0 + scol, Bs + r * 32);
    }
    __syncthreads();
    bf16x8 af[4], bf[4];
#pragma unroll
    for (int i = 0; i < 4; ++i) {
      af[i] = *(const bf16x8*)(As + (wm * 64 + i * 16 + l15) * 32 + g4 * 8);
      bf[i] = *(const bf16x8*)(Bs + (wn * 64 + i * 16 + l15) * 32 + g4 * 8);
    }
#pragma unroll
    for (int i = 0; i < 4; ++i)
#pragma unroll
      for (int j = 0; j < 4; ++j)
        acc[i][j] = __builtin_amdgcn_mfma_f32_16x16x32_bf16(af[i], bf[j],
                                                            acc[i][j], 0, 0, 0);
    __syncthreads();
  }

  // epilogue: C/D layout col=lane&15, row=(lane>>4)*4+reg
  const int rr = g4 * 4;
#pragma unroll
  for (int i = 0; i < 4; ++i) {
#pragma unroll
    for (int j = 0; j < 4; ++j) {
      int row = bm * 128 + wm * 64 + i * 16 + rr;
      int col = bn * 128 + wn * 64 + j * 16 + l15;
#pragma unroll
      for (int r = 0; r < 4; ++r) {
        float v = acc[i][j][r];
        if (Cf != nullptr)
          Cf[(size_t)(row + r) * N + col] = v + bias[col];
        else
          Cb[(size_t)(row + r) * N + col] = f2b(v);
      }
    }
  }
}

struct Gemm3 { const unsigned short* A[3]; const unsigned short* Bt[3];
               unsigned short* C[3]; };

__global__ __launch_bounds__(256) void proj_gemm_kernel(Gemm3 g) {
  int z = blockIdx.z;
  gemm_core(g.A[z], g.Bt[z], g.C[z], nullptr, nullptr);
}

__global__ __launch_bounds__(256) void out_gemm_kernel(
    const unsigned short* __restrict__ A, const unsigned short* __restrict__ Bt,
    float* __restrict__ Cf, const float* __restrict__ bias) {
  gemm_core(A, Bt, nullptr, Cf, bias);
}

// ---------- fused attention: per (q-tile of 64, head, batch) ----------
// 4 waves; wave owns 16 q-rows. KVBLK=64. Swapped QK^T (S^T = K·Q) so each
// lane owns one q-row -> softmax is lane-local (+2 shfl). P redistributed
// to PV A-frags in-register via cvt_pk + 12 shfl (no Ps LDS). Defer-max
// THR=8. Double-buffered K/V via async global_load_lds (pre-swizzled src).
__global__ __launch_bounds__(256) void attn_kernel(
    const unsigned short* __restrict__ q, const unsigned short* __restrict__ k,
    const unsigned short* __restrict__ vt, const int* __restrict__ mask,
    unsigned short* __restrict__ av) {
  extern __shared__ __align__(16) char smem[];
  unsigned short* Ks = (unsigned short*)smem;              // 2 x [64][128] swz
  unsigned short* Vs = (unsigned short*)(smem + 32768);    // 2 x [128][64] swz

  const int tid = threadIdx.x, lane = tid & 63, w = tid >> 6;
  const int qt = blockIdx.x, h = blockIdx.y, b = blockIdx.z;
  const int i0 = qt * 64 + w * 16;
  const int g4 = lane >> 4, l15 = lane & 15;

  // hoist Q fragments (B-operand layout: col=lane&15, k=(lane>>4)*8+j)
  bf16x8 aq[4];
  {
    const unsigned short* qb =
        q + (size_t)(b * TT + i0 + l15) * EE + h * DD + g4 * 8;
#pragma unroll
    for (int kc = 0; kc < 4; ++kc) aq[kc] = *(const bf16x8*)(qb + kc * 32);
  }

  const unsigned short* kb0 = k + (size_t)(b * TT) * EE + h * DD;
  const unsigned short* vb0 = vt + (size_t)((b * HH + h) * DD) * TT;

  // Async stage of tile t into buffer bsel (linear LDS dest, pre-swizzled
  // global source chunk: c ^= row&7 -> reads use addr ^ ((row&7)<<4)).
  auto stage = [&](int t, int bsel) {
    unsigned short* Kd = Ks + bsel * (64 * 128);
    unsigned short* Vd = Vs + bsel * (128 * 64);
#pragma unroll
    for (int p = 0; p < 4; ++p) {
      int base = p * 256 + w * 64;           // wave-uniform 16B-chunk base
      int idx = base + lane;
      int kr = idx >> 4, kc = (idx & 15) ^ (kr & 7);
      gload_lds16(kb0 + (size_t)(t * 64 + kr) * EE + kc * 8, Kd + base * 8);
      int vr = idx >> 3, vc = (idx & 7) ^ (vr & 7);
      gload_lds16(vb0 + (size_t)vr * TT + t * 64 + vc * 8, Vd + base * 8);
    }
  };

  f32x4 oacc[8] = {};
  float mrun = -__builtin_inff(), lrun = 0.f;   // per lane: q-row = l15

  stage(0, 0);
  __syncthreads();   // drains vmcnt -> tile 0 resident
  int buf = 0;

  for (int t = 0; t < 16; ++t) {
    // ---- async prefetch of next tile into the other buffer ----
    if (t < 15) stage(t + 1, buf ^ 1);

    // ---- mask for this tile: int4 per nt (row=l15, cols g4*4..+3) ----
    int4 mreg[4];
    {
      const int* mrow =
          mask + (size_t)(b * TT + i0 + l15) * TT + t * 64 + g4 * 4;
#pragma unroll
      for (int nt = 0; nt < 4; ++nt)
        mreg[nt] = *(const int4*)(mrow + nt * 16);
    }

    const unsigned short* Kb = Ks + buf * 64 * 128;
    const unsigned short* Vb = Vs + buf * 128 * 64;

    // ---- S^T = K Q^T: lane holds q-row l15, kt = nt*16 + g4*4 + r ----
    f32x4 sacc[4];
    __builtin_amdgcn_s_setprio(1);
#pragma unroll
    for (int nt = 0; nt < 4; ++nt) {
      f32x4 s = {};
#pragma unroll
      for (int kc = 0; kc < 4; ++kc) {
        int krow = nt * 16 + l15;
        int addr = (krow * 256 + (kc * 32 + g4 * 8) * 2) ^ ((krow & 7) << 4);
        bf16x8 bk = *(const bf16x8*)((const char*)Kb + addr);
        s = __builtin_amdgcn_mfma_f32_16x16x32_bf16(bk, aq[kc], s, 0, 0, 0);
      }
      sacc[nt] = s;
    }
    __builtin_amdgcn_s_setprio(0);

    // ---- mask (mask==0 -> -1e9) ----
#pragma unroll
    for (int nt = 0; nt < 4; ++nt) {
      if (mreg[nt].x == 0) sacc[nt][0] = -1e9f;
      if (mreg[nt].y == 0) sacc[nt][1] = -1e9f;
      if (mreg[nt].z == 0) sacc[nt][2] = -1e9f;
      if (mreg[nt].w == 0) sacc[nt][3] = -1e9f;
    }

    // ---- row max: local 16 + 2 shfl (combine the 4 g4 kt-quarters) ----
    float mx = sacc[0][0];
#pragma unroll
    for (int nt = 0; nt < 4; ++nt)
#pragma unroll
      for (int r = 0; r < 4; ++r) mx = fmaxf(mx, sacc[nt][r]);
    mx = fmaxf(mx, __shfl_xor(mx, 16, 64));
    mx = fmaxf(mx, __shfl_xor(mx, 32, 64));

    // ---- defer-max (THR=8) ----
    if (__any(mx > mrun + 8.f)) {
      float mnew = fmaxf(mrun, mx);
      float sc = __expf(mrun - mnew);   // exp(-inf)=0 on first tile
      lrun *= sc;
      mrun = mnew;
      float scO[4];
#pragma unroll
      for (int r = 0; r < 4; ++r)
        scO[r] = __shfl(sc, (lane & 48) | (((lane & 48) >> 2) + r), 64);
#pragma unroll
      for (int dt = 0; dt < 8; ++dt)
#pragma unroll
        for (int r = 0; r < 4; ++r) oacc[dt][r] *= scO[r];
    }

    // ---- exp + row sum (lane-local + 2 shfl) ----
    float p[4][4];
    float s0 = 0.f;
#pragma unroll
    for (int nt = 0; nt < 4; ++nt)
#pragma unroll
      for (int r = 0; r < 4; ++r) {
        float pv = __expf(sacc[nt][r] - mrun);   // bounded by e^8
        p[nt][r] = pv;
        s0 += pv;
      }
    s0 += __shfl_xor(s0, 16, 64);
    s0 += __shfl_xor(s0, 32, 64);
    lrun += s0;

    // ---- P -> PV A-frags in-register (cvt_pk + shfl redistribution) ----
    // Lane needs A[row=l15][k=g4*8+j] per 32-kt half; sources hold rows
    // g4'*4+r of each 16-block. 6 shfl_xor (16/32/48) per half.
    unsigned int paw[2][4];
#pragma unroll
    for (int h2 = 0; h2 < 2; ++h2) {
      unsigned int D0a = cvtpk(p[2 * h2][0], p[2 * h2][1]);
      unsigned int D1a = cvtpk(p[2 * h2][2], p[2 * h2][3]);
      unsigned int D0b = cvtpk(p[2 * h2 + 1][0], p[2 * h2 + 1][1]);
      unsigned int D1b = cvtpk(p[2 * h2 + 1][2], p[2 * h2 + 1][3]);
      unsigned int r1 = __shfl_xor(g4 < 2 ? D0a : D0b, 16, 64);
      unsigned int r2 = __shfl_xor(g4 < 2 ? D1a : D1b, 16, 64);
      unsigned int r3 = __shfl_xor(g4 == 0 ? D0b : D0a, 32, 64);
      unsigned int r4 = __shfl_xor(g4 == 0 ? D1b : D1a, 32, 64);
      unsigned int r5 = __shfl_xor(g4 == 2 ? D0a : D0b, 48, 64);
      unsigned int r6 = __shfl_xor(g4 == 2 ? D1a : D1b, 48, 64);
      paw[h2][0] = g4 == 0 ? D0a : g4 == 1 ? r5 : g4 == 2 ? r3 : r1;
      paw[h2][1] = g4 == 0 ? D1a : g4 == 1 ? r6 : g4 == 2 ? r4 : r2;
      paw[h2][2] = g4 == 0 ? r1 : g4 == 1 ? r3 : g4 == 2 ? r5 : D0b;
      paw[h2][3] = g4 == 0 ? r2 : g4 == 1 ? r4 : g4 == 2 ? r6 : D1b;
    }

    // ---- PV: O += P (16x64) @ V (64x128) ----
    __builtin_amdgcn_s_setprio(1);
#pragma unroll
    for (int h2 = 0; h2 < 2; ++h2) {
      union { unsigned int u[4]; bf16x8 v; } pau;
      pau.u[0] = paw[h2][0]; pau.u[1] = paw[h2][1];
      pau.u[2] = paw[h2][2]; pau.u[3] = paw[h2][3];
#pragma unroll
      for (int dt = 0; dt < 8; ++dt) {
        int vrow = dt * 16 + l15;
        int addr = (vrow * 128 + (h2 * 32 + g4 * 8) * 2) ^ ((vrow & 7) << 4);
        bf16x8 bv = *(const bf16x8*)((const char*)Vb + addr);
        oacc[dt] = __builtin_amdgcn_mfma_f32_16x16x32_bf16(pau.v, bv, oacc[dt],
                                                           0, 0, 0);
      }
    }
    __builtin_amdgcn_s_setprio(0);

    // ---- one barrier: drains prefetch (vmcnt) + orders buffer reuse ----
    __syncthreads();
    buf ^= 1;
  }

  // ---- epilogue: att_vec = O / l (l lives at lane l15=qrow; O at g4*4+r) ----
  float linv[4];
#pragma unroll
  for (int r = 0; r < 4; ++r)
    linv[r] = 1.f / __shfl(lrun, (lane & 48) | (((lane & 48) >> 2) + r), 64);
  unsigned short* ob =
      av + (size_t)(b * TT + i0 + g4 * 4) * EE + h * DD + l15;
#pragma unroll
  for (int dt = 0; dt < 8; ++dt)
#pragma unroll
    for (int r = 0; r < 4; ++r)
      ob[(size_t)r * EE + dt * 16] = f2b(oacc[dt][r] * linv[r]);
}

// ---------- launch ----------
extern "C" void kernel_launch(void* const* d_in, const int* in_sizes, int n_in,
                              void* d_out, int out_size, void* d_ws,
                              size_t ws_size, hipStream_t stream) {
  const float* query = (const float*)d_in[0];
  const float* key   = (const float*)d_in[1];
  const int*   mask  = (const int*)d_in[2];
  const float* Wq    = (const float*)d_in[3];
  const float* Wk    = (const float*)d_in[4];
  const float* Wv    = (const float*)d_in[5];
  const float* Wu    = (const float*)d_in[6];
  const float* bu    = (const float*)d_in[7];
  float* out = (float*)d_out;

  char* ws = (char*)d_ws;
  const size_t MB = 1024 * 1024;
  unsigned short* qbf = (unsigned short*)(ws);             // 8MB bf16 query
  unsigned short* kbf = (unsigned short*)(ws + 8 * MB);    // 8MB bf16 key
  unsigned short* Wqt = (unsigned short*)(ws + 16 * MB);   // 2MB each, N x K
  unsigned short* Wkt = (unsigned short*)(ws + 18 * MB);
  unsigned short* Wvt = (unsigned short*)(ws + 20 * MB);
  unsigned short* Wut = (unsigned short*)(ws + 22 * MB);
  unsigned short* qp  = (unsigned short*)(ws + 24 * MB);   // q proj
  unsigned short* kp  = (unsigned short*)(ws + 32 * MB);   // k proj
  unsigned short* vp  = (unsigned short*)(ws + 40 * MB);   // v proj
  unsigned short* vtb = (unsigned short*)(ws + 48 * MB);   // v transposed
  unsigned short* av  = (unsigned short*)(ws + 56 * MB);   // attention out

  cvt_kernel<<<4096, 256, 0, stream>>>(query, key, qbf, kbf);

  WT4 wt; wt.src[0] = Wq; wt.src[1] = Wk; wt.src[2] = Wv; wt.src[3] = Wu;
  wt.dst[0] = Wqt; wt.dst[1] = Wkt; wt.dst[2] = Wvt; wt.dst[3] = Wut;
  wtrans_kernel<<<dim3(32, 32, 4), dim3(32, 8), 0, stream>>>(wt);

  Gemm3 g3;
  g3.A[0] = qbf; g3.A[1] = kbf; g3.A[2] = kbf;
  g3.Bt[0] = Wqt; g3.Bt[1] = Wkt; g3.Bt[2] = Wvt;
  g3.C[0] = qp; g3.C[1] = kp; g3.C[2] = vp;
  proj_gemm_kernel<<<dim3(32, 8, 3), 256, 0, stream>>>(g3);

  vtrans_kernel<<<dim3(4, 32, 32), dim3(32, 8), 0, stream>>>(vp, vtb);

  attn_kernel<<<dim3(16, 8, 4), 256, 65536, stream>>>(qp, kp, vtb, mask, av);

  out_gemm_kernel<<<dim3(32, 8), 256, 0, stream>>>(av, Wut, out, bu);
}

// Round 7
// 119.098 us; speedup vs baseline: 1.4479x; 1.0635x over previous
//
#include <hip/hip_runtime.h>
#include <hip/hip_bf16.h>

// RelativeAttention: out = softmax_j(mask((query@Wq)·(key@Wk)^T)) @ (key@Wv) @ Wu + bu
// B=4, T=1024, E=1024, H=8, D=128. All GEMMs via bf16 MFMA (f32 accum).

typedef __attribute__((ext_vector_type(8))) short bf16x8;   // 8 bf16 (4 VGPRs)
typedef __attribute__((ext_vector_type(4))) float f32x4;    // MFMA C/D frag

static constexpr int BB = 4;
static constexpr int TT = 1024;
static constexpr int EE = 1024;
static constexpr int HH = 8;
static constexpr int DD = 128;

// ---------- helpers ----------
static __device__ __forceinline__ unsigned short f2b(float x) {
  union { float f; unsigned int u; } c; c.f = x;
  unsigned int r = c.u + 0x7fffu + ((c.u >> 16) & 1u);   // RTN-even
  return (unsigned short)(r >> 16);
}

static __device__ __forceinline__ unsigned int cvtpk(float lo, float hi) {
  unsigned int r;
  asm("v_cvt_pk_bf16_f32 %0, %1, %2" : "=v"(r) : "v"(lo), "v"(hi));
  return r;   // low16 = bf16(lo), high16 = bf16(hi)
}

static __device__ __forceinline__ float exp2x(float x) {   // 2^x, 1 instr
  float r;
  asm("v_exp_f32 %0, %1" : "=v"(r) : "v"(x));
  return r;
}

static __device__ __forceinline__ void gload_lds16(const void* g, void* l) {
  __builtin_amdgcn_global_load_lds(
      (const __attribute__((address_space(1))) unsigned int*)g,
      (__attribute__((address_space(3))) unsigned int*)l, 16, 0, 0);
}

// ---------- f32 -> bf16 convert for query & key ----------
__global__ __launch_bounds__(256) void cvt_kernel(
    const float* __restrict__ qf, const float* __restrict__ kf,
    unsigned short* __restrict__ qb, unsigned short* __restrict__ kb) {
  int i = blockIdx.x * 256 + threadIdx.x;   // each thread: 4 elements of each
  float4 a = ((const float4*)qf)[i];
  ushort4 oa; oa.x = f2b(a.x); oa.y = f2b(a.y); oa.z = f2b(a.z); oa.w = f2b(a.w);
  ((ushort4*)qb)[i] = oa;
  float4 b = ((const float4*)kf)[i];
  ushort4 ob; ob.x = f2b(b.x); ob.y = f2b(b.y); ob.z = f2b(b.z); ob.w = f2b(b.w);
  ((ushort4*)kb)[i] = ob;
}

// ---------- weight transpose-convert: W (K x N) f32 -> Wt (N x K) bf16 ----------
// scale folds log2(e) into Wq so softmax can run in exp2 domain.
struct WT4 { const float* src[4]; unsigned short* dst[4]; float scale[4]; };

__global__ __launch_bounds__(256) void wtrans_kernel(WT4 wt) {
  const float* src = wt.src[blockIdx.z];
  unsigned short* dst = wt.dst[blockIdx.z];
  const float sc = wt.scale[blockIdx.z];
  __shared__ float tile[32][33];
  int n0 = blockIdx.x * 32, k0 = blockIdx.y * 32;
  int tx = threadIdx.x, ty = threadIdx.y;   // (32, 8)
#pragma unroll
  for (int i = 0; i < 4; ++i)
    tile[ty + i * 8][tx] = src[(size_t)(k0 + ty + i * 8) * EE + n0 + tx];
  __syncthreads();
#pragma unroll
  for (int i = 0; i < 4; ++i)
    dst[(size_t)(n0 + ty + i * 8) * EE + k0 + tx] = f2b(tile[tx][ty + i * 8] * sc);
}

// ---------- V transpose: vp [b,kt, h*128+d] -> vt [b,h,d, kt] (bf16) ----------
__global__ __launch_bounds__(256) void vtrans_kernel(
    const unsigned short* __restrict__ vp, unsigned short* __restrict__ vt) {
  int bh = blockIdx.z; int b = bh >> 3, h = bh & 7;
  int d0 = blockIdx.x * 32, kt0 = blockIdx.y * 32;
  __shared__ unsigned short tile[32][33];
  int tx = threadIdx.x, ty = threadIdx.y;
#pragma unroll
  for (int i = 0; i < 4; ++i)
    tile[ty + i * 8][tx] =
        vp[(size_t)(b * TT + kt0 + ty + i * 8) * EE + h * DD + d0 + tx];
  __syncthreads();
#pragma unroll
  for (int i = 0; i < 4; ++i)
    vt[(size_t)((b * HH + h) * DD + d0 + ty + i * 8) * TT + kt0 + tx] =
        tile[tx][ty + i * 8];
}

// ---------- mask -> bitmask: mbits[row][t] bit j = (mask[row][t*64+j] != 0) ----
__global__ __launch_bounds__(256) void maskpack_kernel(
    const int* __restrict__ mask, unsigned long long* __restrict__ mbits) {
  int row = blockIdx.x * 4 + (threadIdx.x >> 6);   // row < B*TT = 4096
  int lane = threadIdx.x & 63;
  const int* mrow = mask + (size_t)row * TT;
  unsigned long long myw = 0;
#pragma unroll
  for (int jw = 0; jw < 16; ++jw) {
    unsigned long long bal = __ballot(mrow[jw * 64 + lane] != 0);
    if (lane == jw) myw = bal;
  }
  if (lane < 16) mbits[(size_t)row * 16 + lane] = myw;
}

// ---------- GEMM core (bf16 out): C[M,N] = A[M,K] @ Bt[N,K]^T  (m97) ----------
// 128x128 tile, BK=32, 4 waves (2x2), 4x4 16x16 fragments per wave.
static __device__ __forceinline__ void gemm_core(
    const unsigned short* __restrict__ A, const unsigned short* __restrict__ Bt,
    unsigned short* __restrict__ Cb) {
  constexpr int K = EE, N = EE;
  __shared__ __align__(16) unsigned short As[128 * 32];
  __shared__ __align__(16) unsigned short Bs[128 * 32];
  const int tid = threadIdx.x, lane = tid & 63, w = tid >> 6;
  const int wm = w >> 1, wn = w & 1;
  const int bm = blockIdx.x, bn = blockIdx.y;
  const int g4 = lane >> 4, l15 = lane & 15;
  const int srow = lane >> 2;            // 0..15 (row within 16-row chunk)
  const int scol = (lane & 3) * 8;       // bf16 elems within 64B row

  f32x4 acc[4][4] = {};

  for (int kt = 0; kt < K / 32; ++kt) {
    const int k0 = kt * 32;
#pragma unroll
    for (int it = 0; it < 2; ++it) {
      int r = it * 64 + w * 16;
      gload_lds16(A + (size_t)(bm * 128 + r + srow) * K + k0 + scol, As + r * 32);
      gload_lds16(Bt + (size_t)(bn * 128 + r + srow) * K + k0 + scol, Bs + r * 32);
    }
    __syncthreads();
    bf16x8 af[4], bf[4];
#pragma unroll
    for (int i = 0; i < 4; ++i) {
      af[i] = *(const bf16x8*)(As + (wm * 64 + i * 16 + l15) * 32 + g4 * 8);
      bf[i] = *(const bf16x8*)(Bs + (wn * 64 + i * 16 + l15) * 32 + g4 * 8);
    }
#pragma unroll
    for (int i = 0; i < 4; ++i)
#pragma unroll
      for (int j = 0; j < 4; ++j)
        acc[i][j] = __builtin_amdgcn_mfma_f32_16x16x32_bf16(af[i], bf[j],
                                                            acc[i][j], 0, 0, 0);
    __syncthreads();
  }

  // epilogue: C/D layout col=lane&15, row=(lane>>4)*4+reg
  const int rr = g4 * 4;
#pragma unroll
  for (int i = 0; i < 4; ++i)
#pragma unroll
    for (int j = 0; j < 4; ++j) {
      int row = bm * 128 + wm * 64 + i * 16 + rr;
      int col = bn * 128 + wn * 64 + j * 16 + l15;
#pragma unroll
      for (int r = 0; r < 4; ++r)
        Cb[(size_t)(row + r) * N + col] = f2b(acc[i][j][r]);
    }
}

struct Gemm3 { const unsigned short* A[3]; const unsigned short* Bt[3];
               unsigned short* C[3]; };

__global__ __launch_bounds__(256) void proj_gemm_kernel(Gemm3 g) {
  int z = blockIdx.z;
  gemm_core(g.A[z], g.Bt[z], g.C[z]);
}

// ---------- output GEMM: 64x128 tile (512 blocks -> 2 blocks/CU) ----------
__global__ __launch_bounds__(256) void out_gemm_kernel(
    const unsigned short* __restrict__ A, const unsigned short* __restrict__ Bt,
    float* __restrict__ Cf, const float* __restrict__ bias) {
  constexpr int K = EE, N = EE;
  __shared__ __align__(16) unsigned short As[64 * 32];
  __shared__ __align__(16) unsigned short Bs[128 * 32];
  const int tid = threadIdx.x, lane = tid & 63, w = tid >> 6;
  const int wm = w >> 1, wn = w & 1;
  const int bm = blockIdx.x, bn = blockIdx.y;
  const int g4 = lane >> 4, l15 = lane & 15;

  f32x4 acc[2][4] = {};

  for (int kt = 0; kt < K / 32; ++kt) {
    const int k0 = kt * 32;
    {
      int row = tid >> 2, c = tid & 3;               // A: 256 x 16B chunks
      gload_lds16(A + (size_t)(bm * 64 + row) * K + k0 + c * 8, As + tid * 8);
    }
#pragma unroll
    for (int it = 0; it < 2; ++it) {                 // B: 512 x 16B chunks
      int idx = it * 256 + tid;
      int row = idx >> 2, c = idx & 3;
      gload_lds16(Bt + (size_t)(bn * 128 + row) * K + k0 + c * 8, Bs + idx * 8);
    }
    __syncthreads();
    bf16x8 af[2], bf[4];
#pragma unroll
    for (int i = 0; i < 2; ++i)
      af[i] = *(const bf16x8*)(As + (wm * 32 + i * 16 + l15) * 32 + g4 * 8);
#pragma unroll
    for (int j = 0; j < 4; ++j)
      bf[j] = *(const bf16x8*)(Bs + (wn * 64 + j * 16 + l15) * 32 + g4 * 8);
#pragma unroll
    for (int i = 0; i < 2; ++i)
#pragma unroll
      for (int j = 0; j < 4; ++j)
        acc[i][j] = __builtin_amdgcn_mfma_f32_16x16x32_bf16(af[i], bf[j],
                                                            acc[i][j], 0, 0, 0);
    __syncthreads();
  }

  const int rr = g4 * 4;
#pragma unroll
  for (int i = 0; i < 2; ++i)
#pragma unroll
    for (int j = 0; j < 4; ++j) {
      int row = bm * 64 + wm * 32 + i * 16 + rr;
      int col = bn * 128 + wn * 64 + j * 16 + l15;
#pragma unroll
      for (int r = 0; r < 4; ++r)
        Cf[(size_t)(row + r) * N + col] = acc[i][j][r] + bias[col];
    }
}

// ---------- fused attention ----------
// 4 waves x 16 q-rows, KVBLK=64, swapped QK^T (lane owns q-row = l15),
// exp2-domain softmax (Wq pre-scaled by log2 e), defer-max THR=8,
// bitmask (1 ulong/lane/tile), strength-reduced staging pointers,
// base+imm ds_read addressing, dbuf K/V via async global_load_lds.
__global__ __launch_bounds__(256) void attn_kernel(
    const unsigned short* __restrict__ q, const unsigned short* __restrict__ k,
    const unsigned short* __restrict__ vt,
    const unsigned long long* __restrict__ mbits,
    unsigned short* __restrict__ av) {
  extern __shared__ __align__(16) char smem[];   // [0,32K) K dbuf; [32K,64K) V dbuf

  const int tid = threadIdx.x, lane = tid & 63, w = tid >> 6;
  const int qt = blockIdx.x, h = blockIdx.y, b = blockIdx.z;
  const int i0 = qt * 64 + w * 16;
  const int g4 = lane >> 4, l15 = lane & 15;
  const int swz = (l15 & 7) << 4;

  // Q fragments (operand layout: elem row=lane&15, k=(lane>>4)*8+j)
  bf16x8 aq[4];
  {
    const unsigned short* qb =
        q + (size_t)(b * TT + i0 + l15) * EE + h * DD + g4 * 8;
#pragma unroll
    for (int kc = 0; kc < 4; ++kc) aq[kc] = *(const bf16x8*)(qb + kc * 32);
  }

  // staging source pointers: computed once, advanced by constant per tile.
  // Global source chunk pre-swizzled (c ^= row&7) so LDS dest stays linear
  // and reads use the XOR'd base (both-sides involution, guide item 21).
  const unsigned short* kb0 = k + (size_t)(b * TT) * EE + h * DD;
  const unsigned short* vb0 = vt + (size_t)((b * HH + h) * DD) * TT;
  const unsigned short* kptr[4];
  const unsigned short* vptr[4];
  int chunkb[4];
#pragma unroll
  for (int p = 0; p < 4; ++p) {
    int base = p * 256 + w * 64;           // wave-uniform 16B-chunk base
    int idx = base + lane;
    int kr = idx >> 4, kcc = (idx & 15) ^ (kr & 7);
    kptr[p] = kb0 + (size_t)kr * EE + kcc * 8;
    int vr = idx >> 3, vcc = (idx & 7) ^ (vr & 7);
    vptr[p] = vb0 + (size_t)vr * TT + vcc * 8;
    chunkb[p] = base * 16;                 // byte offset in LDS
  }

  // mask bit words: word t covers kt in [t*64, t*64+64), bit = kt&63
  const unsigned long long* mb = mbits + ((size_t)(b * TT + i0 + l15) << 4);
  unsigned long long mcur = mb[0];

  // LDS read bases (byte): addr = kb_[kc] + nt*4096 ; vb_[h2] + dt*2048.
  // Valid because (krow&7)==(l15&7) indep. of nt, and the XOR bits (4..6)
  // don't overlap nt*4096 / l15*256 / dt*2048 / l15*128.
  int kb_[4], vb_[2];
#pragma unroll
  for (int kc = 0; kc < 4; ++kc)
    kb_[kc] = l15 * 256 + ((kc * 64 + g4 * 16) ^ swz);
#pragma unroll
  for (int h2 = 0; h2 < 2; ++h2)
    vb_[h2] = 32768 + l15 * 128 + ((h2 * 64 + g4 * 16) ^ swz);

  // prologue: stage tile 0 into buf 0
#pragma unroll
  for (int p = 0; p < 4; ++p) {
    gload_lds16(kptr[p], smem + chunkb[p]);
    gload_lds16(vptr[p], smem + 32768 + chunkb[p]);
  }
#pragma unroll
  for (int p = 0; p < 4; ++p) { kptr[p] += 64 * EE; vptr[p] += 64; }

  f32x4 oacc[8] = {};
  float mrun = -__builtin_inff(), lrun = 0.f;   // per lane: q-row = l15

  __syncthreads();
  int bufoff = 0;   // byte offset of current K buffer (0 / 16384)

  for (int t = 0; t < 16; ++t) {
    // ---- next tile: mask word first (so its wait is a counted vmcnt),
    //      then async K/V prefetch into the other buffer ----
    unsigned long long mnext = 0;
    if (t < 15) {
      mnext = mb[t + 1];
      int dst = bufoff ^ 16384;
#pragma unroll
      for (int p = 0; p < 4; ++p) {
        gload_lds16(kptr[p], smem + dst + chunkb[p]);
        gload_lds16(vptr[p], smem + 32768 + dst + chunkb[p]);
      }
#pragma unroll
      for (int p = 0; p < 4; ++p) { kptr[p] += 64 * EE; vptr[p] += 64; }
    }

    // ---- S^T = K Q^T: lane holds q-row l15, kt = nt*16 + g4*4 + r ----
    f32x4 sacc[4] = {};
    __builtin_amdgcn_s_setprio(1);
#pragma unroll
    for (int kc = 0; kc < 4; ++kc)
#pragma unroll
      for (int nt = 0; nt < 4; ++nt) {
        bf16x8 bk = *(const bf16x8*)(smem + kb_[kc] + nt * 4096);
        sacc[nt] = __builtin_amdgcn_mfma_f32_16x16x32_bf16(bk, aq[kc],
                                                           sacc[nt], 0, 0, 0);
      }
    __builtin_amdgcn_s_setprio(0);

    // ---- mask: bit==0 -> -1e9 (exp2 of it underflows to 0) ----
    {
      unsigned int wlo = (unsigned int)mcur, whi = (unsigned int)(mcur >> 32);
#pragma unroll
      for (int nt = 0; nt < 4; ++nt) {
        unsigned int ww = (nt < 2) ? wlo : whi;
        int bb = (nt & 1) * 16 + g4 * 4;
#pragma unroll
        for (int r = 0; r < 4; ++r)
          if (((ww >> (bb + r)) & 1u) == 0u) sacc[nt][r] = -1e9f;
      }
    }

    // ---- row max: lane-local 16 + 2 shfl ----
    float mx = sacc[0][0];
#pragma unroll
    for (int nt = 0; nt < 4; ++nt)
#pragma unroll
      for (int r = 0; r < 4; ++r) mx = fmaxf(mx, sacc[nt][r]);
    mx = fmaxf(mx, __shfl_xor(mx, 16, 64));
    mx = fmaxf(mx, __shfl_xor(mx, 32, 64));

    // ---- defer-max (THR=8 in log2 domain -> P bounded by 256) ----
    if (__any(mx > mrun + 8.f)) {
      float mnew = fmaxf(mrun, mx);
      float sc = exp2x(mrun - mnew);   // exp2(-inf)=0 on first tile
      lrun *= sc;
      mrun = mnew;
      float scO[4];
#pragma unroll
      for (int r = 0; r < 4; ++r)
        scO[r] = __shfl(sc, (lane & 48) | (((lane & 48) >> 2) + r), 64);
#pragma unroll
      for (int dt = 0; dt < 8; ++dt)
#pragma unroll
        for (int r = 0; r < 4; ++r) oacc[dt][r] *= scO[r];
    }

    // ---- exp2 + row sum (lane-local + 2 shfl) ----
    float p[4][4];
    float s0 = 0.f;
#pragma unroll
    for (int nt = 0; nt < 4; ++nt)
#pragma unroll
      for (int r = 0; r < 4; ++r) {
        float pv = exp2x(sacc[nt][r] - mrun);
        p[nt][r] = pv;
        s0 += pv;
      }
    s0 += __shfl_xor(s0, 16, 64);
    s0 += __shfl_xor(s0, 32, 64);
    lrun += s0;

    // ---- P -> PV A-frags in-register (cvt_pk + 12 shfl) ----
    unsigned int paw[2][4];
#pragma unroll
    for (int h2 = 0; h2 < 2; ++h2) {
      unsigned int D0a = cvtpk(p[2 * h2][0], p[2 * h2][1]);
      unsigned int D1a = cvtpk(p[2 * h2][2], p[2 * h2][3]);
      unsigned int D0b = cvtpk(p[2 * h2 + 1][0], p[2 * h2 + 1][1]);
      unsigned int D1b = cvtpk(p[2 * h2 + 1][2], p[2 * h2 + 1][3]);
      unsigned int r1 = __shfl_xor(g4 < 2 ? D0a : D0b, 16, 64);
      unsigned int r2 = __shfl_xor(g4 < 2 ? D1a : D1b, 16, 64);
      unsigned int r3 = __shfl_xor(g4 == 0 ? D0b : D0a, 32, 64);
      unsigned int r4 = __shfl_xor(g4 == 0 ? D1b : D1a, 32, 64);
      unsigned int r5 = __shfl_xor(g4 == 2 ? D0a : D0b, 48, 64);
      unsigned int r6 = __shfl_xor(g4 == 2 ? D1a : D1b, 48, 64);
      paw[h2][0] = g4 == 0 ? D0a : g4 == 1 ? r5 : g4 == 2 ? r3 : r1;
      paw[h2][1] = g4 == 0 ? D1a : g4 == 1 ? r6 : g4 == 2 ? r4 : r2;
      paw[h2][2] = g4 == 0 ? r1 : g4 == 1 ? r3 : g4 == 2 ? r5 : D0b;
      paw[h2][3] = g4 == 0 ? r2 : g4 == 1 ? r4 : g4 == 2 ? r6 : D1b;
    }

    // ---- PV: O += P (16x64) @ V (64x128) ----
    __builtin_amdgcn_s_setprio(1);
#pragma unroll
    for (int h2 = 0; h2 < 2; ++h2) {
      union { unsigned int u[4]; bf16x8 v; } pau;
      pau.u[0] = paw[h2][0]; pau.u[1] = paw[h2][1];
      pau.u[2] = paw[h2][2]; pau.u[3] = paw[h2][3];
#pragma unroll
      for (int dt = 0; dt < 8; ++dt) {
        bf16x8 bv = *(const bf16x8*)(smem + vb_[h2] + dt * 2048);
        oacc[dt] = __builtin_amdgcn_mfma_f32_16x16x32_bf16(pau.v, bv, oacc[dt],
                                                           0, 0, 0);
      }
    }
    __builtin_amdgcn_s_setprio(0);

    // ---- one barrier: drains prefetch + orders buffer reuse ----
    __syncthreads();
    bufoff ^= 16384;
#pragma unroll
    for (int kc = 0; kc < 4; ++kc) kb_[kc] ^= 16384;
#pragma unroll
    for (int h2 = 0; h2 < 2; ++h2) vb_[h2] ^= 16384;
    mcur = mnext;
  }

  // ---- epilogue: att_vec = O / l (l at lane l15=qrow; O rows at g4*4+r) ----
  float linv[4];
#pragma unroll
  for (int r = 0; r < 4; ++r)
    linv[r] = 1.f / __shfl(lrun, (lane & 48) | (((lane & 48) >> 2) + r), 64);
  unsigned short* ob =
      av + (size_t)(b * TT + i0 + g4 * 4) * EE + h * DD + l15;
#pragma unroll
  for (int dt = 0; dt < 8; ++dt)
#pragma unroll
    for (int r = 0; r < 4; ++r)
      ob[(size_t)r * EE + dt * 16] = f2b(oacc[dt][r] * linv[r]);
}

// ---------- launch ----------
extern "C" void kernel_launch(void* const* d_in, const int* in_sizes, int n_in,
                              void* d_out, int out_size, void* d_ws,
                              size_t ws_size, hipStream_t stream) {
  const float* query = (const float*)d_in[0];
  const float* key   = (const float*)d_in[1];
  const int*   mask  = (const int*)d_in[2];
  const float* Wq    = (const float*)d_in[3];
  const float* Wk    = (const float*)d_in[4];
  const float* Wv    = (const float*)d_in[5];
  const float* Wu    = (const float*)d_in[6];
  const float* bu    = (const float*)d_in[7];
  float* out = (float*)d_out;

  char* ws = (char*)d_ws;
  const size_t MB = 1024 * 1024;
  unsigned short* qbf = (unsigned short*)(ws);             // 8MB bf16 query
  unsigned short* kbf = (unsigned short*)(ws + 8 * MB);    // 8MB bf16 key
  unsigned short* Wqt = (unsigned short*)(ws + 16 * MB);   // 2MB each, N x K
  unsigned short* Wkt = (unsigned short*)(ws + 18 * MB);
  unsigned short* Wvt = (unsigned short*)(ws + 20 * MB);
  unsigned short* Wut = (unsigned short*)(ws + 22 * MB);
  unsigned short* qp  = (unsigned short*)(ws + 24 * MB);   // q proj
  unsigned short* kp  = (unsigned short*)(ws + 32 * MB);   // k proj
  unsigned short* vp  = (unsigned short*)(ws + 40 * MB);   // v proj (dead after vtrans)
  unsigned short* vtb = (unsigned short*)(ws + 48 * MB);   // v transposed
  unsigned short* av  = (unsigned short*)(ws + 56 * MB);   // attention out
  unsigned long long* mbt = (unsigned long long*)(ws + 40 * MB);  // 512KB, reuses vp

  cvt_kernel<<<4096, 256, 0, stream>>>(query, key, qbf, kbf);

  WT4 wt; wt.src[0] = Wq; wt.src[1] = Wk; wt.src[2] = Wv; wt.src[3] = Wu;
  wt.dst[0] = Wqt; wt.dst[1] = Wkt; wt.dst[2] = Wvt; wt.dst[3] = Wut;
  wt.scale[0] = 1.4426950408889634f;   // log2(e): softmax in exp2 domain
  wt.scale[1] = 1.0f; wt.scale[2] = 1.0f; wt.scale[3] = 1.0f;
  wtrans_kernel<<<dim3(32, 32, 4), dim3(32, 8), 0, stream>>>(wt);

  Gemm3 g3;
  g3.A[0] = qbf; g3.A[1] = kbf; g3.A[2] = kbf;
  g3.Bt[0] = Wqt; g3.Bt[1] = Wkt; g3.Bt[2] = Wvt;
  g3.C[0] = qp; g3.C[1] = kp; g3.C[2] = vp;
  proj_gemm_kernel<<<dim3(32, 8, 3), 256, 0, stream>>>(g3);

  vtrans_kernel<<<dim3(4, 32, 32), dim3(32, 8), 0, stream>>>(vp, vtb);

  // after vtrans, vp region is dead -> pack mask bits there
  maskpack_kernel<<<1024, 256, 0, stream>>>(mask, mbt);

  attn_kernel<<<dim3(16, 8, 4), 256, 65536, stream>>>(qp, kp, vtb, mbt, av);

  out_gemm_kernel<<<dim3(64, 8), 256, 0, stream>>>(av, Wut, out, bu);
}